// Round 11
// baseline (305.030 us; speedup 1.0000x reference)
//
#include <hip/hip_runtime.h>
#include <math.h>

#define S_LEN 512
#define BATCH 256
#define NTAG  128
#define EMSTRIDE (BATCH * NTAG)  /* floats per time step */

typedef float f32x2 __attribute__((ext_vector_type(2)));
typedef float f32x4 __attribute__((ext_vector_type(4)));

__device__ __forceinline__ f32x2 fma2(f32x2 a, f32x2 b, f32x2 c){
  f32x2 r; r[0]=__builtin_fmaf(a[0],b[0],c[0]); r[1]=__builtin_fmaf(a[1],b[1],c[1]); return r;
}
__device__ __forceinline__ float max3f(float a, float b, float c){
  return fmaxf(fmaxf(a,b),c);   // -> v_max3_f32
}

#define DPPF(x, ctrl) __uint_as_float(__builtin_amdgcn_mov_dpp(__float_as_uint(x), ctrl, 0xF, 0xF, false))
#define RL(x, m)      __uint_as_float(__builtin_amdgcn_readlane(__float_as_uint(x), m))

// full wave64 max (positive values), all VALU: quad xor1/xor2, row ror4/ror8,
// then row_bcast15/row_bcast31; lane 63 holds the wave max -> readlane.
__device__ __forceinline__ float wavemax_pos(float x) {
  x = fmaxf(x, DPPF(x, 0xB1));   // quad_perm xor1
  x = fmaxf(x, DPPF(x, 0x4E));   // quad_perm xor2
  x = fmaxf(x, DPPF(x, 0x124));  // row_ror:4
  x = fmaxf(x, DPPF(x, 0x128));  // row_ror:8
  x = fmaxf(x, DPPF(x, 0x142));  // row_bcast15
  x = fmaxf(x, DPPF(x, 0x143));  // row_bcast31
  return RL(x, 63);
}

__device__ __forceinline__ int emt(bool isR, int len, int i) {
  int s = isR ? (len - 2 - i) : (1 + i);
  s = s < 0 ? 0 : s;
  return s > S_LEN - 1 ? S_LEN - 1 : s;
}

// ---------------------------------------------------------------------------
// Chain kernel: grid = 2*BATCH, 256 threads, __launch_bounds__(256,1) so each
// wave gets a full SIMD and up to 512 VGPRs.
//   blk < BATCH : 4 independent chain WAVES for batch b=blk:
//                 wave 0=fwd-left, 1=fwd-right, 2=vit-left, 3=vit-right
//                 (meet at sm=(len-1)>>1; left cnt=sm, right cnt=len-1-sm).
//   blk >= BATCH: gold-path block for b=blk-BATCH.
// Per chain wave: NO LDS, NO barriers. Lane l owns state (w[2l],w[2l+1]) and
// output rows 2l,2l+1; E/T rows live in 256 f32 VGPRs. Broadcast of state k
// to all lanes = v_readlane (VALU), consumed as SGPR operand of v_pk_fma_f32
// (fwd, exp space) / v_pk_add_f32 + v_max3_f32 (viterbi, log space, exact).
// Fwd renorm every 4th step: DPP wave max + scalar exponent math, exact pow2.
// ---------------------------------------------------------------------------
__global__ __launch_bounds__(256, 1)
void crf_chain_kernel(const float* __restrict__ emis,
                      const float* __restrict__ mask,
                      const int* __restrict__ tags,
                      const float* __restrict__ trans,
                      const float* __restrict__ startt,
                      const float* __restrict__ stopt,
                      float* __restrict__ ws,
                      int* __restrict__ ewbuf,
                      float* __restrict__ out)
{
  const int blk = blockIdx.x;
  const int tid = threadIdx.x;

  __shared__ float red[16];

  // ---------------- gold role ----------------
  if (blk >= BATCH) {
    const int b = blk - BATCH;
    float part = 0.f, lenp = 0.f;
#pragma unroll
    for (int rep = 0; rep < 2; ++rep) {
      int s = tid + rep * 256;
      float m  = mask[(size_t)s * BATCH + b];
      int  cur = tags[(size_t)s * BATCH + b];
      if (s == 0) {
        part += startt[cur] + emis[(size_t)b * NTAG + cur] * m;
      } else {
        int prev = tags[(size_t)(s - 1) * BATCH + b];
        part += m * (trans[(size_t)prev * NTAG + cur] +
                     emis[((size_t)s * BATCH + b) * NTAG + cur]);
      }
      lenp += m;
    }
#pragma unroll
    for (int d = 1; d <= 32; d <<= 1) {
      part += __shfl_xor(part, d);
      lenp += __shfl_xor(lenp, d);
    }
    const int lane = tid & 63, wid = tid >> 6;
    if (lane == 0) { red[wid] = part; red[8 + wid] = lenp; }
    __syncthreads();
    if (tid == 0) {
      float rps = (red[0] + red[1]) + (red[2] + red[3]);
      float lf  = (red[8] + red[9]) + (red[10] + red[11]);
      int len = (int)(lf + 0.5f);
      int pf  = tags[(size_t)(len - 1) * BATCH + b];
      out[1 + b] = rps + stopt[pf];
    }
    return;
  }

  const int  b    = blk;
  const int  role = tid >> 6;      // wave id, uniform per wave
  const int  l    = tid & 63;
  const bool isR  = (role & 1) != 0;
  const bool isV  = (role >= 2);

  // ---- len = sum_s mask[s,b] (mask monotone), per-wave butterfly ----
  float mv = 0.f;
#pragma unroll
  for (int r = 0; r < 8; ++r) mv += mask[(size_t)(l + 64 * r) * BATCH + b];
#pragma unroll
  for (int d = 1; d <= 32; d <<= 1) mv += __shfl_xor(mv, d);
  const int len = (int)(mv + 0.5f);

  const int sm  = (len - 1) >> 1;
  const int nst = len - 1 - sm;
  const int cnt = isR ? nst : sm;

  // ---- M0/M1: my two rows of E (fwd: exp'd) or T, k-pair packed ----
  // left : M0[m] = (T[2l][2m],   T[2l][2m+1]),   M1 = row 2l+1
  // right: M0[m] = (T[2m][2l],   T[2m+1][2l]),   M1 = col 2l+1 (transposed)
  f32x2 M0[64], M1[64];
  if (!isR) {
    const float* r0 = trans + (size_t)(2 * l) * NTAG;
    const float* r1 = r0 + NTAG;
#pragma unroll
    for (int m = 0; m < 64; ++m) {
      M0[m] = *(const f32x2*)(r0 + 2 * m);
      M1[m] = *(const f32x2*)(r1 + 2 * m);
    }
  } else {
    const float* tc = trans + 2 * l;
#pragma unroll
    for (int m = 0; m < 64; ++m) {
      f32x2 p0 = *(const f32x2*)(tc + (size_t)(2 * m) * NTAG);
      f32x2 p1 = *(const f32x2*)(tc + (size_t)(2 * m + 1) * NTAG);
      f32x2 a; a[0] = p0[0]; a[1] = p1[0];
      f32x2 c; c[0] = p0[1]; c[1] = p1[1];
      M0[m] = a; M1[m] = c;
    }
  }
  if (!isV) {
#pragma unroll
    for (int m = 0; m < 64; ++m) {
      M0[m][0] = __expf(M0[m][0]); M0[m][1] = __expf(M0[m][1]);
      M1[m][0] = __expf(M1[m][0]); M1[m][1] = __expf(M1[m][1]);
    }
  }

  // ---- init state (lane-local pair) ----
  const float* ebm = emis + (size_t)b * NTAG + 2 * l;
  float w0, w1;
  {
    f32x2 s0;
    if (!isR) {
      f32x2 st = *(const f32x2*)(startt + 2 * l);
      s0 = st + *(const f32x2*)ebm;
    } else {
      f32x2 st = *(const f32x2*)(stopt + 2 * l);
      f32x2 eL = {0.f, 0.f};
      if (nst > 0) eL = *(const f32x2*)(ebm + (size_t)(len - 1) * EMSTRIDE);
      s0 = st + eL;
    }
    w0 = isV ? s0[0] : __expf(s0[0]);
    w1 = isV ? s0[1] : __expf(s0[1]);
  }
  int Ew = 0;

  // ---- emission prefetch depth 4 ----
  f32x2 e0 = *(const f32x2*)(ebm + (size_t)emt(isR, len, 0) * EMSTRIDE);
  f32x2 e1 = *(const f32x2*)(ebm + (size_t)emt(isR, len, 1) * EMSTRIDE);
  f32x2 e2 = *(const f32x2*)(ebm + (size_t)emt(isR, len, 2) * EMSTRIDE);
  f32x2 e3 = *(const f32x2*)(ebm + (size_t)emt(isR, len, 3) * EMSTRIDE);

#define STEP(U, EV, RN)                                                       \
  {                                                                           \
    const int i_ = gb + (U);                                                  \
    if (i_ >= cnt) goto epi;                                                  \
    const bool lastR_ = isR && (i_ == cnt - 1);                               \
    if (!isV) {                                                               \
      f32x2 aA0 = {0.f,0.f}, aA1 = {0.f,0.f};                                 \
      f32x2 aB0 = {0.f,0.f}, aB1 = {0.f,0.f};                                 \
      _Pragma("unroll")                                                       \
      for (int m = 0; m < 64; ++m) {                                          \
        f32x2 sp; sp[0] = RL(w0, m); sp[1] = RL(w1, m);                       \
        if (m & 1) { aA1 = fma2(M0[m], sp, aA1); aB1 = fma2(M1[m], sp, aB1); }\
        else       { aA0 = fma2(M0[m], sp, aA0); aB0 = fma2(M1[m], sp, aB0); }\
      }                                                                       \
      f32x2 aA = aA0 + aA1, aB = aB0 + aB1;                                   \
      float sA = aA[0] + aA[1], sB = aB[0] + aB[1];                           \
      float ex0 = 1.f, ex1 = 1.f;                                             \
      if (!lastR_) { ex0 = __expf((EV)[0]); ex1 = __expf((EV)[1]); }          \
      if (RN) {                                                               \
        float mx_ = wavemax_pos(fmaxf(w0, w1));                               \
        int ew_ = (int)((__float_as_uint(mx_) >> 23) & 0xFF) - 126;           \
        Ew += ew_;                                                            \
        float sc_ = __uint_as_float((unsigned)(127 - ew_) << 23);             \
        w0 = ex0 * sA * sc_; w1 = ex1 * sB * sc_;                             \
      } else {                                                                \
        w0 = ex0 * sA; w1 = ex1 * sB;                                         \
      }                                                                       \
    } else {                                                                  \
      float mA0 = -3.0e38f, mA1 = -3.0e38f;                                   \
      float mB0 = -3.0e38f, mB1 = -3.0e38f;                                   \
      _Pragma("unroll")                                                       \
      for (int m = 0; m < 64; ++m) {                                          \
        f32x2 sp; sp[0] = RL(w0, m); sp[1] = RL(w1, m);                       \
        f32x2 t0 = sp + M0[m];                                                \
        f32x2 t1 = sp + M1[m];                                                \
        if (m & 1) { mA1 = max3f(mA1, t0[0], t0[1]);                          \
                     mB1 = max3f(mB1, t1[0], t1[1]); }                        \
        else       { mA0 = max3f(mA0, t0[0], t0[1]);                          \
                     mB0 = max3f(mB0, t1[0], t1[1]); }                        \
      }                                                                       \
      float sA = fmaxf(mA0, mA1), sB = fmaxf(mB0, mB1);                       \
      w0 = lastR_ ? sA : sA + (EV)[0];                                        \
      w1 = lastR_ ? sB : sB + (EV)[1];                                        \
    }                                                                         \
  }

  for (int gb = 0; gb < 256; gb += 4) {
    f32x2 n0 = *(const f32x2*)(ebm + (size_t)emt(isR, len, gb + 4) * EMSTRIDE);
    f32x2 n1 = *(const f32x2*)(ebm + (size_t)emt(isR, len, gb + 5) * EMSTRIDE);
    f32x2 n2 = *(const f32x2*)(ebm + (size_t)emt(isR, len, gb + 6) * EMSTRIDE);
    f32x2 n3 = *(const f32x2*)(ebm + (size_t)emt(isR, len, gb + 7) * EMSTRIDE);

    STEP(0, e0, 0)
    STEP(1, e1, 0)
    STEP(2, e2, 0)
    STEP(3, e3, 1)   // fwd renorm every 4th step (growth < 2^90, fp32-safe)

    e0 = n0; e1 = n1; e2 = n2; e3 = n3;
  }

epi:
  {
    f32x2 o; o[0] = w0; o[1] = w1;
    *(f32x2*)(ws + (size_t)b * 512 + role * 128 + 2 * l) = o;
    if (l == 0 && !isV) ewbuf[(role & 1) * BATCH + b] = Ew;
  }
}

// ---------------------------------------------------------------------------
// Combine: total = (EwFL+EwFR)ln2 + log(sum_k WL*WR); best = max_k(VL+VR).
// ---------------------------------------------------------------------------
__global__ __launch_bounds__(128, 1)
void crf_combine_kernel(const float* __restrict__ ws,
                        const int* __restrict__ ewbuf,
                        float* __restrict__ out)
{
  const int b = blockIdx.x, k = threadIdx.x;
  const float* base = ws + (size_t)b * 512;
  float t1 = base[k] * base[128 + k];
  float m1 = base[256 + k] + base[384 + k];
#pragma unroll
  for (int d = 1; d <= 32; d <<= 1) {
    t1 += __shfl_xor(t1, d);
    m1 = fmaxf(m1, __shfl_xor(m1, d));
  }
  __shared__ float rs[2], rm[2];
  const int lane = k & 63, wid = k >> 6;
  if (lane == 0) { rs[wid] = t1; rm[wid] = m1; }
  __syncthreads();
  if (k == 0) {
    const double LN2 = 0.6931471805599453;
    int Et = ewbuf[b] + ewbuf[BATCH + b];
    out[1 + BATCH + b]     = (float)((double)Et * LN2 + (double)__logf(rs[0] + rs[1]));
    out[1 + 2 * BATCH + b] = fmaxf(rm[0], rm[1]);
  }
}

// ---------------------------------------------------------------------------
// loss = mean(total_score - real_path_score)
// ---------------------------------------------------------------------------
__global__ __launch_bounds__(256, 1)
void crf_loss_kernel(float* __restrict__ out)
{
  const int tid = threadIdx.x;
  float dft = out[1 + BATCH + tid] - out[1 + tid];
#pragma unroll
  for (int d = 1; d <= 32; d <<= 1) dft += __shfl_xor(dft, d);
  __shared__ float rs[4];
  const int lane = tid & 63, wid = tid >> 6;
  if (lane == 0) rs[wid] = dft;
  __syncthreads();
  if (tid == 0)
    out[0] = ((rs[0] + rs[1]) + (rs[2] + rs[3])) * (1.0f / BATCH);
}

extern "C" void kernel_launch(void* const* d_in, const int* in_sizes, int n_in,
                              void* d_out, int out_size, void* d_ws, size_t ws_size,
                              hipStream_t stream)
{
  const float* emis   = (const float*)d_in[0];
  const float* mask   = (const float*)d_in[1];
  const int*   tags   = (const int*)d_in[2];
  const float* trans  = (const float*)d_in[3];
  const float* startt = (const float*)d_in[4];
  const float* stopt  = (const float*)d_in[5];
  float* out = (float*)d_out;

  float* wsf   = (float*)d_ws;                 // 256 * 512 floats
  int*   ewbuf = (int*)(wsf + 512 * BATCH);    // 2 * 256 ints

  crf_chain_kernel<<<2 * BATCH, 256, 0, stream>>>(emis, mask, tags, trans,
                                                  startt, stopt, wsf, ewbuf, out);
  crf_combine_kernel<<<BATCH, 128, 0, stream>>>(wsf, ewbuf, out);
  crf_loss_kernel<<<1, 256, 0, stream>>>(out);
}

// Round 12
// 247.805 us; speedup vs baseline: 1.2309x; 1.2309x over previous
//
#include <hip/hip_runtime.h>
#include <math.h>

#define S_LEN 512
#define BATCH 256
#define NTAG  128
#define EMSTRIDE (BATCH * NTAG)  /* floats per time step */

typedef float    f32x2 __attribute__((ext_vector_type(2)));
typedef _Float16 h16x2 __attribute__((ext_vector_type(2)));

#define DPPF(x, ctrl) __uint_as_float(__builtin_amdgcn_mov_dpp(__float_as_uint(x), ctrl, 0xF, 0xF, false))
#define RLI(x, m)     __builtin_amdgcn_readlane((x), (m))
#define RLU(x, m)     ((unsigned)__builtin_amdgcn_readlane((int)__float_as_uint(x), (m)))

__device__ __forceinline__ unsigned umaxu(unsigned a, unsigned b) { return a > b ? a : b; }

__device__ __forceinline__ int pkmax(int a, int b) {
  int r; asm("v_pk_max_f16 %0, %1, %2" : "=v"(r) : "v"(a), "v"(b)); return r;
}
__device__ __forceinline__ int pkmul(int a, int b) {
  int r; asm("v_pk_mul_f16 %0, %1, %2" : "=v"(r) : "v"(a), "v"(b)); return r;
}
__device__ __forceinline__ float dot2(int e, int s, float c) {
  return __builtin_amdgcn_fdot2(__builtin_bit_cast(h16x2, e),
                                __builtin_bit_cast(h16x2, s), c, false);
}
__device__ __forceinline__ int packh(float a, float b) {
  return __builtin_bit_cast(int, __builtin_amdgcn_cvt_pkrtz(a, b));
}
__device__ __forceinline__ f32x2 unpackh(int p) {
  h16x2 h = __builtin_bit_cast(h16x2, p);
  f32x2 r; r[0] = (float)h[0]; r[1] = (float)h[1]; return r;
}
__device__ __forceinline__ int emt(bool isR, int len, int i) {
  int s = isR ? (len - 2 - i) : (1 + i);
  s = s < 0 ? 0 : s;
  return s > S_LEN - 1 ? S_LEN - 1 : s;
}

// ---------------------------------------------------------------------------
// Chain kernel: grid = 2*BATCH, 256 threads, launch_bounds(256,1).
//   blk < BATCH : 4 independent chain WAVES for batch b=blk:
//     wave 0=fwd-left, 1=fwd-right, 2=vit-left, 3=vit-right
//     (meet at sm=(len-1)>>1; left cnt=sm, right cnt=len-1-sm). ALL exp-space.
//   blk >= BATCH: gold-path block.
// Per chain wave: NO LDS, NO barriers, NO spill. Lane l owns state pair
// (w[2l],w[2l+1]) packed f16 in ONE reg and output rows 2l,2l+1; matrix
// exp(T) as 128 packed-f16 VGPRs. Broadcast = 64 v_readlane/step feeding
// v_dot2_f32_f16 (fwd, f32 accum) / v_pk_mul+v_pk_max_f16 (viterbi).
// Renorm every step (exact pow2): 4 DPP maxes -> 4 readlanes -> SALU umax;
// exponent accumulated in scalar Ew.
// ---------------------------------------------------------------------------
__global__ __launch_bounds__(256, 1)
void crf_chain_kernel(const float* __restrict__ emis,
                      const float* __restrict__ mask,
                      const int* __restrict__ tags,
                      const float* __restrict__ trans,
                      const float* __restrict__ startt,
                      const float* __restrict__ stopt,
                      float* __restrict__ ws,
                      int* __restrict__ ewbuf,
                      float* __restrict__ out)
{
  const int blk = blockIdx.x;
  const int tid = threadIdx.x;

  __shared__ float red[16];

  // ---------------- gold role ----------------
  if (blk >= BATCH) {
    const int b = blk - BATCH;
    float part = 0.f, lenp = 0.f;
#pragma unroll
    for (int rep = 0; rep < 2; ++rep) {
      int s = tid + rep * 256;
      float m  = mask[(size_t)s * BATCH + b];
      int  cur = tags[(size_t)s * BATCH + b];
      if (s == 0) {
        part += startt[cur] + emis[(size_t)b * NTAG + cur] * m;
      } else {
        int prev = tags[(size_t)(s - 1) * BATCH + b];
        part += m * (trans[(size_t)prev * NTAG + cur] +
                     emis[((size_t)s * BATCH + b) * NTAG + cur]);
      }
      lenp += m;
    }
#pragma unroll
    for (int d = 1; d <= 32; d <<= 1) {
      part += __shfl_xor(part, d);
      lenp += __shfl_xor(lenp, d);
    }
    const int lane = tid & 63, wid = tid >> 6;
    if (lane == 0) { red[wid] = part; red[8 + wid] = lenp; }
    __syncthreads();
    if (tid == 0) {
      float rps = (red[0] + red[1]) + (red[2] + red[3]);
      float lf  = (red[8] + red[9]) + (red[10] + red[11]);
      int len = (int)(lf + 0.5f);
      int pf  = tags[(size_t)(len - 1) * BATCH + b];
      out[1 + b] = rps + stopt[pf];
    }
    return;
  }

  const int  b    = blk;
  const int  role = tid >> 6;      // wave id, uniform per wave
  const int  l    = tid & 63;
  const bool isR  = (role & 1) != 0;
  const bool isV  = (role >= 2);

  // ---- len = sum_s mask[s,b] (mask monotone), per-wave butterfly ----
  float mv = 0.f;
#pragma unroll
  for (int r = 0; r < 8; ++r) mv += mask[(size_t)(l + 64 * r) * BATCH + b];
#pragma unroll
  for (int d = 1; d <= 32; d <<= 1) mv += __shfl_xor(mv, d);
  const int len = (int)(mv + 0.5f);

  const int sm  = (len - 1) >> 1;
  const int nst = len - 1 - sm;
  const int cnt = isR ? nst : sm;

  // ---- matrix: exp(T) rows (left) / cols (right) as packed f16 ----
  // EP0[m] = (M[2l][2m], M[2l][2m+1]); EP1 = row 2l+1.  right: M = T^T.
  int EP0[64], EP1[64];
  if (!isR) {
    const float* r0 = trans + (size_t)(2 * l) * NTAG;
    const float* r1 = r0 + NTAG;
#pragma unroll
    for (int m = 0; m < 64; ++m) {
      f32x2 p = *(const f32x2*)(r0 + 2 * m);
      f32x2 q = *(const f32x2*)(r1 + 2 * m);
      EP0[m] = packh(__expf(p[0]), __expf(p[1]));
      EP1[m] = packh(__expf(q[0]), __expf(q[1]));
    }
  } else {
    const float* tc = trans + 2 * l;
#pragma unroll
    for (int m = 0; m < 64; ++m) {
      f32x2 p0 = *(const f32x2*)(tc + (size_t)(2 * m) * NTAG);
      f32x2 p1 = *(const f32x2*)(tc + (size_t)(2 * m + 1) * NTAG);
      EP0[m] = packh(__expf(p0[0]), __expf(p1[0]));
      EP1[m] = packh(__expf(p0[1]), __expf(p1[1]));
    }
  }

  // ---- init state (exp space, pow2-normalized, packed f16) ----
  const float* ebm = emis + (size_t)b * NTAG + 2 * l;
  int Ew, wpk;
  {
    f32x2 s0;
    if (!isR) {
      f32x2 st = *(const f32x2*)(startt + 2 * l);
      s0 = st + *(const f32x2*)ebm;
    } else {
      f32x2 st = *(const f32x2*)(stopt + 2 * l);
      f32x2 eL = {0.f, 0.f};
      if (nst > 0) eL = *(const f32x2*)(ebm + (size_t)(len - 1) * EMSTRIDE);
      s0 = st + eL;
    }
    float u0 = __expf(s0[0]), u1 = __expf(s0[1]);
    float mx = fmaxf(u0, u1);
    mx = fmaxf(mx, DPPF(mx, 0xB1));
    mx = fmaxf(mx, DPPF(mx, 0x4E));
    mx = fmaxf(mx, DPPF(mx, 0x124));
    mx = fmaxf(mx, DPPF(mx, 0x128));
    unsigned rb = umaxu(umaxu(RLU(mx, 0), RLU(mx, 16)),
                        umaxu(RLU(mx, 32), RLU(mx, 48)));
    int eb = (int)((rb >> 23) & 0xFF);
    Ew = eb - 126;
    float sc = __uint_as_float((unsigned)(253 - eb) << 23);
    wpk = packh(u0 * sc, u1 * sc);
  }

  // ---- emission prefetch depth 4 ----
  f32x2 e0 = *(const f32x2*)(ebm + (size_t)emt(isR, len, 0) * EMSTRIDE);
  f32x2 e1 = *(const f32x2*)(ebm + (size_t)emt(isR, len, 1) * EMSTRIDE);
  f32x2 e2 = *(const f32x2*)(ebm + (size_t)emt(isR, len, 2) * EMSTRIDE);
  f32x2 e3 = *(const f32x2*)(ebm + (size_t)emt(isR, len, 3) * EMSTRIDE);

#define STEP(U, EV)                                                           \
  {                                                                           \
    const int i_ = gb + (U);                                                  \
    if (i_ >= cnt) goto epi;                                                  \
    const bool lastR_ = isR && (i_ == cnt - 1);                               \
    float ex0_ = 1.f, ex1_ = 1.f;                                             \
    if (!lastR_) { ex0_ = __expf((EV)[0]); ex1_ = __expf((EV)[1]); }          \
    float v0_, v1_;                                                           \
    if (!isV) {                                                               \
      float a0_=0.f,a1_=0.f,a2_=0.f,a3_=0.f;                                  \
      float c0_=0.f,c1_=0.f,c2_=0.f,c3_=0.f;                                  \
      _Pragma("unroll")                                                       \
      for (int m = 0; m < 16; ++m) {                                          \
        int s0_ = RLI(wpk, 4*m), s1_ = RLI(wpk, 4*m+1);                       \
        int s2_ = RLI(wpk, 4*m+2), s3_ = RLI(wpk, 4*m+3);                     \
        a0_ = dot2(EP0[4*m],   s0_, a0_); c0_ = dot2(EP1[4*m],   s0_, c0_);   \
        a1_ = dot2(EP0[4*m+1], s1_, a1_); c1_ = dot2(EP1[4*m+1], s1_, c1_);   \
        a2_ = dot2(EP0[4*m+2], s2_, a2_); c2_ = dot2(EP1[4*m+2], s2_, c2_);   \
        a3_ = dot2(EP0[4*m+3], s3_, a3_); c3_ = dot2(EP1[4*m+3], s3_, c3_);   \
      }                                                                       \
      v0_ = ex0_ * ((a0_ + a1_) + (a2_ + a3_));                               \
      v1_ = ex1_ * ((c0_ + c1_) + (c2_ + c3_));                               \
    } else {                                                                  \
      int p0_=0,p1_=0,p2_=0,p3_=0,q0_=0,q1_=0,q2_=0,q3_=0;                    \
      _Pragma("unroll")                                                       \
      for (int m = 0; m < 16; ++m) {                                          \
        int s0_ = RLI(wpk, 4*m), s1_ = RLI(wpk, 4*m+1);                       \
        int s2_ = RLI(wpk, 4*m+2), s3_ = RLI(wpk, 4*m+3);                     \
        p0_ = pkmax(p0_, pkmul(EP0[4*m],   s0_));                             \
        q0_ = pkmax(q0_, pkmul(EP1[4*m],   s0_));                             \
        p1_ = pkmax(p1_, pkmul(EP0[4*m+1], s1_));                             \
        q1_ = pkmax(q1_, pkmul(EP1[4*m+1], s1_));                             \
        p2_ = pkmax(p2_, pkmul(EP0[4*m+2], s2_));                             \
        q2_ = pkmax(q2_, pkmul(EP1[4*m+2], s2_));                             \
        p3_ = pkmax(p3_, pkmul(EP0[4*m+3], s3_));                             \
        q3_ = pkmax(q3_, pkmul(EP1[4*m+3], s3_));                             \
      }                                                                       \
      int pm_ = pkmax(pkmax(p0_, p1_), pkmax(p2_, p3_));                      \
      int qm_ = pkmax(pkmax(q0_, q1_), pkmax(q2_, q3_));                      \
      f32x2 pf_ = unpackh(pm_), qf_ = unpackh(qm_);                           \
      v0_ = ex0_ * fmaxf(pf_[0], pf_[1]);                                     \
      v1_ = ex1_ * fmaxf(qf_[0], qf_[1]);                                     \
    }                                                                         \
    float mx_ = fmaxf(v0_, v1_);                                              \
    mx_ = fmaxf(mx_, DPPF(mx_, 0xB1));                                        \
    mx_ = fmaxf(mx_, DPPF(mx_, 0x4E));                                        \
    mx_ = fmaxf(mx_, DPPF(mx_, 0x124));                                       \
    mx_ = fmaxf(mx_, DPPF(mx_, 0x128));                                       \
    unsigned rb_ = umaxu(umaxu(RLU(mx_, 0), RLU(mx_, 16)),                    \
                         umaxu(RLU(mx_, 32), RLU(mx_, 48)));                  \
    int eb_ = (int)((rb_ >> 23) & 0xFF);                                      \
    Ew += eb_ - 126;                                                          \
    float sc_ = __uint_as_float((unsigned)(253 - eb_) << 23);                 \
    wpk = packh(v0_ * sc_, v1_ * sc_);                                        \
  }

  for (int gb = 0; gb < 256; gb += 4) {
    f32x2 n0 = *(const f32x2*)(ebm + (size_t)emt(isR, len, gb + 4) * EMSTRIDE);
    f32x2 n1 = *(const f32x2*)(ebm + (size_t)emt(isR, len, gb + 5) * EMSTRIDE);
    f32x2 n2 = *(const f32x2*)(ebm + (size_t)emt(isR, len, gb + 6) * EMSTRIDE);
    f32x2 n3 = *(const f32x2*)(ebm + (size_t)emt(isR, len, gb + 7) * EMSTRIDE);

    STEP(0, e0)
    STEP(1, e1)
    STEP(2, e2)
    STEP(3, e3)

    e0 = n0; e1 = n1; e2 = n2; e3 = n3;
  }

epi:
  {
    f32x2 o = unpackh(wpk);
    *(f32x2*)(ws + (size_t)b * 512 + role * 128 + 2 * l) = o;
    if (l == 0) ewbuf[role * BATCH + b] = Ew;
  }
}

// ---------------------------------------------------------------------------
// Combine: total = (EwFL+EwFR)ln2 + log(sum_k WL*WR);
//          best  = (EwVL+EwVR)ln2 + log(max_k VL*VR).
// ---------------------------------------------------------------------------
__global__ __launch_bounds__(128, 1)
void crf_combine_kernel(const float* __restrict__ ws,
                        const int* __restrict__ ewbuf,
                        float* __restrict__ out)
{
  const int b = blockIdx.x, k = threadIdx.x;
  const float* base = ws + (size_t)b * 512;
  float t1 = base[k] * base[128 + k];
  float m1 = base[256 + k] * base[384 + k];
#pragma unroll
  for (int d = 1; d <= 32; d <<= 1) {
    t1 += __shfl_xor(t1, d);
    m1 = fmaxf(m1, __shfl_xor(m1, d));
  }
  __shared__ float rs[2], rm[2];
  const int lane = k & 63, wid = k >> 6;
  if (lane == 0) { rs[wid] = t1; rm[wid] = m1; }
  __syncthreads();
  if (k == 0) {
    const double LN2 = 0.6931471805599453;
    int EtF = ewbuf[b] + ewbuf[BATCH + b];
    int EtV = ewbuf[2 * BATCH + b] + ewbuf[3 * BATCH + b];
    out[1 + BATCH + b] =
        (float)((double)EtF * LN2 + (double)__logf(rs[0] + rs[1]));
    out[1 + 2 * BATCH + b] =
        (float)((double)EtV * LN2 + (double)__logf(fmaxf(rm[0], rm[1])));
  }
}

// ---------------------------------------------------------------------------
// loss = mean(total_score - real_path_score)
// ---------------------------------------------------------------------------
__global__ __launch_bounds__(256, 1)
void crf_loss_kernel(float* __restrict__ out)
{
  const int tid = threadIdx.x;
  float dft = out[1 + BATCH + tid] - out[1 + tid];
#pragma unroll
  for (int d = 1; d <= 32; d <<= 1) dft += __shfl_xor(dft, d);
  __shared__ float rs[4];
  const int lane = tid & 63, wid = tid >> 6;
  if (lane == 0) rs[wid] = dft;
  __syncthreads();
  if (tid == 0)
    out[0] = ((rs[0] + rs[1]) + (rs[2] + rs[3])) * (1.0f / BATCH);
}

extern "C" void kernel_launch(void* const* d_in, const int* in_sizes, int n_in,
                              void* d_out, int out_size, void* d_ws, size_t ws_size,
                              hipStream_t stream)
{
  const float* emis   = (const float*)d_in[0];
  const float* mask   = (const float*)d_in[1];
  const int*   tags   = (const int*)d_in[2];
  const float* trans  = (const float*)d_in[3];
  const float* startt = (const float*)d_in[4];
  const float* stopt  = (const float*)d_in[5];
  float* out = (float*)d_out;

  float* wsf   = (float*)d_ws;                 // 256 * 512 floats
  int*   ewbuf = (int*)(wsf + 512 * BATCH);    // 4 * 256 ints

  crf_chain_kernel<<<2 * BATCH, 256, 0, stream>>>(emis, mask, tags, trans,
                                                  startt, stopt, wsf, ewbuf, out);
  crf_combine_kernel<<<BATCH, 128, 0, stream>>>(wsf, ewbuf, out);
  crf_loss_kernel<<<1, 256, 0, stream>>>(out);
}